// Round 1
// baseline (299.961 us; speedup 1.0000x reference)
//
#include <hip/hip_runtime.h>
#include <cstdint>
#include <cstddef>

#define NH 16
#define DK 64
#define DM 1024
#define SEQL 2048
#define NB 2
#define NR (NB * SEQL)   // 4096 token rows

typedef short bf16x8 __attribute__((ext_vector_type(8)));
typedef float f32x4 __attribute__((ext_vector_type(4)));

static __device__ __forceinline__ float bf2f(short u) {
  union { unsigned int i; float f; } x;
  x.i = ((unsigned int)(unsigned short)u) << 16;
  return x.f;
}
static __device__ __forceinline__ short f2bf(float f) {
  union { unsigned int i; float f; } x;
  x.f = f;
  unsigned int r = x.i + 0x7fffu + ((x.i >> 16) & 1u);  // RNE
  return (short)(r >> 16);
}

static __device__ __forceinline__ void store_out(float* p, float v) { *p = v; }
static __device__ __forceinline__ void store_out(short* p, float v) { *p = f2bf(v); }

// ---------------- fp32 -> bf16 conversion (vectorized) ----------------
__global__ void cvt_f32_bf16(const float* __restrict__ in, short* __restrict__ out, int n) {
  int i = (blockIdx.x * blockDim.x + threadIdx.x) * 4;
  if (i >= n) return;
  float4 v = *reinterpret_cast<const float4*>(in + i);
  short4 o;
  o.x = f2bf(v.x); o.y = f2bf(v.y); o.z = f2bf(v.z); o.w = f2bf(v.w);
  *reinterpret_cast<short4*>(out + i) = o;
}

// ---------------- RoPE cos/sin table: [2048 pos][32 freq] ----------------
__global__ void rope_table_kernel(float2* __restrict__ tab) {
  int idx = blockIdx.x * blockDim.x + threadIdx.x;  // pos*32 + j
  int pos = idx >> 5, j = idx & 31;
  float freq = powf(10000.0f, -(float)j / 32.0f);   // theta^(-2j/64)
  float ang = (float)pos * freq;
  tab[idx] = make_float2(cosf(ang), sinf(ang));
}

// ---------------- RoPE apply in-place on bf16 [NR][DM] ----------------
__global__ void rope_apply_kernel(short* __restrict__ buf, const int* __restrict__ pos,
                                  const float2* __restrict__ tab) {
  int p = blockIdx.x * blockDim.x + threadIdx.x;  // [0, NR*512)
  int row = p >> 9, pr = p & 511;
  int h = pr >> 5, j = pr & 31;
  int col = h * 64 + 2 * j;
  short* q = buf + (size_t)row * DM + col;
  short2 v = *reinterpret_cast<short2*>(q);
  float2 cs = tab[pos[row] * 32 + j];
  float xe = bf2f(v.x), xo = bf2f(v.y);
  short2 o;
  o.x = f2bf(xe * cs.x - xo * cs.y);
  o.y = f2bf(xe * cs.y + xo * cs.x);
  *reinterpret_cast<short2*>(q) = o;
}

// ---------------- bf16 GEMM: C[M][N] = A[M][K] * B[N][K]^T ----------------
// 128x128 tile, BK=32, 4 waves (each 64x64 = 4x4 mfma_16x16x32 frags).
template <typename OutT>
static __device__ __forceinline__ void gemm_body(const short* __restrict__ A,
                                                 const short* __restrict__ B,
                                                 OutT* __restrict__ C,
                                                 int m0, int n0, int N, int K) {
  __shared__ short As[128][40];  // +8 pad: 80B row stride, 16B aligned, 2-way banks (free)
  __shared__ short Bs[128][40];
  const int t = threadIdx.x;
  const int wid = t >> 6, lane = t & 63;
  const int wr = wid >> 1, wc = wid & 1;
  const int lrow = lane & 15, lk = lane >> 4;

  f32x4 acc[4][4];
#pragma unroll
  for (int i = 0; i < 4; ++i)
#pragma unroll
    for (int j = 0; j < 4; ++j) acc[i][j] = (f32x4){0.f, 0.f, 0.f, 0.f};

  for (int k0 = 0; k0 < K; k0 += 32) {
    __syncthreads();
#pragma unroll
    for (int p = 0; p < 2; ++p) {
      int c = p * 256 + t;           // 512 chunks of 8 bf16 cover 128x32
      int row = c >> 2, kc = (c & 3) * 8;
      *reinterpret_cast<bf16x8*>(&As[row][kc]) =
          *reinterpret_cast<const bf16x8*>(&A[(size_t)(m0 + row) * K + k0 + kc]);
      *reinterpret_cast<bf16x8*>(&Bs[row][kc]) =
          *reinterpret_cast<const bf16x8*>(&B[(size_t)(n0 + row) * K + k0 + kc]);
    }
    __syncthreads();
    bf16x8 af[4], bfr[4];
#pragma unroll
    for (int i = 0; i < 4; ++i) {
      af[i] = *reinterpret_cast<const bf16x8*>(&As[wr * 64 + i * 16 + lrow][lk * 8]);
      bfr[i] = *reinterpret_cast<const bf16x8*>(&Bs[wc * 64 + i * 16 + lrow][lk * 8]);
    }
#pragma unroll
    for (int i = 0; i < 4; ++i)
#pragma unroll
      for (int j = 0; j < 4; ++j)
        acc[i][j] = __builtin_amdgcn_mfma_f32_16x16x32_bf16(af[i], bfr[j], acc[i][j], 0, 0, 0);
  }
  // C/D layout: col = lane&15, row = (lane>>4)*4 + r   [m89-verified]
#pragma unroll
  for (int i = 0; i < 4; ++i)
#pragma unroll
    for (int j = 0; j < 4; ++j) {
      int row = m0 + wr * 64 + i * 16 + lk * 4;
      int col = n0 + wc * 64 + j * 16 + lrow;
#pragma unroll
      for (int r = 0; r < 4; ++r) store_out(&C[(size_t)(row + r) * N + col], acc[i][j][r]);
    }
}

__global__ __launch_bounds__(256) void qkv_gemm_kernel(
    const short* __restrict__ X, const short* __restrict__ Wq, const short* __restrict__ Wk,
    const short* __restrict__ Wv, short* __restrict__ Q, short* __restrict__ K,
    short* __restrict__ V) {
  int nb = blockIdx.x;  // 0..23 : 8 n-blocks per weight
  const short* B = (nb < 8) ? Wq : (nb < 16) ? Wk : Wv;
  short* C = (nb < 8) ? Q : (nb < 16) ? K : V;
  gemm_body<short>(X, B, C, blockIdx.y * 128, (nb & 7) * 128, DM, DM);
}

__global__ __launch_bounds__(256) void out_gemm_kernel(const short* __restrict__ A,
                                                       const short* __restrict__ W,
                                                       float* __restrict__ C) {
  gemm_body<float>(A, W, C, blockIdx.y * 128, blockIdx.x * 128, DM, DM);
}

// ---------------- causal flash attention ----------------
// grid: (S/64, B*H). 4 waves/block, each wave owns 16 q rows. KBLK = 64.
__global__ __launch_bounds__(256) void attn_kernel(const short* __restrict__ Q,
                                                   const short* __restrict__ K,
                                                   const short* __restrict__ V,
                                                   short* __restrict__ O) {
  __shared__ short Ks[64][72];        // K tile [k][d], +8 pad
  __shared__ short Vt[64][72];        // V tile transposed [d][k]
  __shared__ short Ps[4][16][72];     // per-wave P round-trip
  const int t = threadIdx.x;
  const int wid = t >> 6, lane = t & 63;
  const int lrow = lane & 15, lk = lane >> 4;
  const int qt = blockIdx.x, bh = blockIdx.y;
  const int b = bh >> 4, h = bh & 15;
  const size_t base = (size_t)b * SEQL * DM + (size_t)h * DK;

  // Q fragments held in registers for the whole block row
  bf16x8 aq[2];
  {
    int qrow = qt * 64 + wid * 16 + lrow;
#pragma unroll
    for (int c = 0; c < 2; ++c)
      aq[c] = *reinterpret_cast<const bf16x8*>(&Q[base + (size_t)qrow * DM + c * 32 + lk * 8]);
  }

  f32x4 oacc[4];
#pragma unroll
  for (int g = 0; g < 4; ++g) oacc[g] = (f32x4){0.f, 0.f, 0.f, 0.f};
  float mrow[4] = {-1e30f, -1e30f, -1e30f, -1e30f};
  float lsum[4] = {0.f, 0.f, 0.f, 0.f};
  const int qg0 = qt * 64 + wid * 16 + lk * 4;  // + r gives global q index

  for (int kt = 0; kt <= qt; ++kt) {
    __syncthreads();  // protect Ks/Vt from previous iteration's readers
    // stage K tile (as-is) and V tile (transposed)
#pragma unroll
    for (int p = 0; p < 2; ++p) {
      int c = p * 256 + t;  // 512 chunks of 8 bf16 cover 64x64
      int krow = c >> 3, doff = (c & 7) * 8;
      size_t gaddr = base + (size_t)(kt * 64 + krow) * DM + doff;
      bf16x8 kv = *reinterpret_cast<const bf16x8*>(&K[gaddr]);
      *reinterpret_cast<bf16x8*>(&Ks[krow][doff]) = kv;
      bf16x8 vv = *reinterpret_cast<const bf16x8*>(&V[gaddr]);
#pragma unroll
      for (int e = 0; e < 8; ++e) Vt[doff + e][krow] = vv[e];
    }
    __syncthreads();

    // S = Q K^T  (per wave: 16q x 64k as 4 n-groups)
    f32x4 s[4];
#pragma unroll
    for (int g = 0; g < 4; ++g) {
      bf16x8 b0 = *reinterpret_cast<const bf16x8*>(&Ks[g * 16 + lrow][lk * 8]);
      bf16x8 b1 = *reinterpret_cast<const bf16x8*>(&Ks[g * 16 + lrow][32 + lk * 8]);
      f32x4 z = (f32x4){0.f, 0.f, 0.f, 0.f};
      z = __builtin_amdgcn_mfma_f32_16x16x32_bf16(aq[0], b0, z, 0, 0, 0);
      s[g] = __builtin_amdgcn_mfma_f32_16x16x32_bf16(aq[1], b1, z, 0, 0, 0);
    }

    const bool diag = (kt == qt);
#pragma unroll
    for (int g = 0; g < 4; ++g)
#pragma unroll
      for (int r = 0; r < 4; ++r) {
        float v = s[g][r] * 0.125f;  // 1/sqrt(64)
        if (diag && (kt * 64 + g * 16 + lrow) > (qg0 + r)) v = -1e30f;
        s[g][r] = v;
      }

    // online softmax: row m = lk*4 + r lives across the 16 lanes sharing lk
    float pv[4][4];
#pragma unroll
    for (int r = 0; r < 4; ++r) {
      float mx = fmaxf(fmaxf(s[0][r], s[1][r]), fmaxf(s[2][r], s[3][r]));
#pragma unroll
      for (int off = 1; off < 16; off <<= 1) mx = fmaxf(mx, __shfl_xor(mx, off));
      float mnew = fmaxf(mrow[r], mx);
      float alpha = __expf(mrow[r] - mnew);
      float psum = 0.f;
#pragma unroll
      for (int g = 0; g < 4; ++g) {
        float p = __expf(s[g][r] - mnew);
        pv[g][r] = p;
        psum += p;
      }
#pragma unroll
      for (int off = 1; off < 16; off <<= 1) psum += __shfl_xor(psum, off);
      lsum[r] = lsum[r] * alpha + psum;
      mrow[r] = mnew;
#pragma unroll
      for (int g = 0; g < 4; ++g) oacc[g][r] *= alpha;
    }

    // P -> LDS (C/D layout -> A-operand layout round trip)
#pragma unroll
    for (int g = 0; g < 4; ++g)
#pragma unroll
      for (int r = 0; r < 4; ++r) Ps[wid][lk * 4 + r][g * 16 + lrow] = f2bf(pv[g][r]);
    __syncthreads();  // also orders the per-wave LDS write->read

    bf16x8 pa[2];
#pragma unroll
    for (int c = 0; c < 2; ++c)
      pa[c] = *reinterpret_cast<const bf16x8*>(&Ps[wid][lrow][c * 32 + lk * 8]);
#pragma unroll
    for (int g = 0; g < 4; ++g) {
      bf16x8 v0 = *reinterpret_cast<const bf16x8*>(&Vt[g * 16 + lrow][lk * 8]);
      bf16x8 v1 = *reinterpret_cast<const bf16x8*>(&Vt[g * 16 + lrow][32 + lk * 8]);
      oacc[g] = __builtin_amdgcn_mfma_f32_16x16x32_bf16(pa[0], v0, oacc[g], 0, 0, 0);
      oacc[g] = __builtin_amdgcn_mfma_f32_16x16x32_bf16(pa[1], v1, oacc[g], 0, 0, 0);
    }
  }

#pragma unroll
  for (int g = 0; g < 4; ++g)
#pragma unroll
    for (int r = 0; r < 4; ++r) {
      float v = oacc[g][r] / lsum[r];
      O[base + (size_t)(qt * 64 + wid * 16 + lk * 4 + r) * DM + g * 16 + lrow] = f2bf(v);
    }
}

// ---------------- host launch ----------------
extern "C" void kernel_launch(void* const* d_in, const int* in_sizes, int n_in,
                              void* d_out, int out_size, void* d_ws, size_t ws_size,
                              hipStream_t stream) {
  const float* x = (const float*)d_in[0];
  const float* wq = (const float*)d_in[1];
  const float* wk = (const float*)d_in[2];
  const float* wv = (const float*)d_in[3];
  const float* wo = (const float*)d_in[4];
  const int* tpos = (const int*)d_in[5];
  float* out = (float*)d_out;

  char* w = (char*)d_ws;
  short* xb = (short*)w;  w += (size_t)NR * DM * 2;
  short* wqb = (short*)w; w += (size_t)DM * DM * 2;
  short* wkb = (short*)w; w += (size_t)DM * DM * 2;
  short* wvb = (short*)w; w += (size_t)DM * DM * 2;
  short* wob = (short*)w; w += (size_t)DM * DM * 2;
  short* Qb = (short*)w;  w += (size_t)NR * DM * 2;
  short* Kb = (short*)w;  w += (size_t)NR * DM * 2;
  short* Vb = (short*)w;  w += (size_t)NR * DM * 2;
  short* Ob = (short*)w;  w += (size_t)NR * DM * 2;
  float2* tab = (float2*)w;

  cvt_f32_bf16<<<NR * DM / 1024, 256, 0, stream>>>(x, xb, NR * DM);
  cvt_f32_bf16<<<DM * DM / 1024, 256, 0, stream>>>(wq, wqb, DM * DM);
  cvt_f32_bf16<<<DM * DM / 1024, 256, 0, stream>>>(wk, wkb, DM * DM);
  cvt_f32_bf16<<<DM * DM / 1024, 256, 0, stream>>>(wv, wvb, DM * DM);
  cvt_f32_bf16<<<DM * DM / 1024, 256, 0, stream>>>(wo, wob, DM * DM);
  rope_table_kernel<<<2048 * 32 / 256, 256, 0, stream>>>(tab);
  qkv_gemm_kernel<<<dim3(24, NR / 128), 256, 0, stream>>>(xb, wqb, wkb, wvb, Qb, Kb, Vb);
  rope_apply_kernel<<<NR * 512 / 256, 256, 0, stream>>>(Qb, tpos, tab);
  rope_apply_kernel<<<NR * 512 / 256, 256, 0, stream>>>(Kb, tpos, tab);
  attn_kernel<<<dim3(SEQL / 64, NB * NH), 256, 0, stream>>>(Qb, Kb, Vb, Ob);
  out_gemm_kernel<<<dim3(DM / 128, NR / 128), 256, 0, stream>>>(Ob, wob, out);
}

// Round 2
// 167.634 us; speedup vs baseline: 1.7894x; 1.7894x over previous
//
#include <hip/hip_runtime.h>
#include <cstdint>
#include <cstddef>

#define NH 16
#define DK 64
#define DM 1024
#define SEQL 2048
#define NB 2
#define NR (NB * SEQL)   // 4096 token rows

typedef short bf16x8 __attribute__((ext_vector_type(8)));
typedef float f32x4 __attribute__((ext_vector_type(4)));

static __device__ __forceinline__ float bf2f(short u) {
  union { unsigned int i; float f; } x;
  x.i = ((unsigned int)(unsigned short)u) << 16;
  return x.f;
}
static __device__ __forceinline__ short f2bf(float f) {
  union { unsigned int i; float f; } x;
  x.f = f;
  unsigned int r = x.i + 0x7fffu + ((x.i >> 16) & 1u);  // RNE
  return (short)(r >> 16);
}

static __device__ __forceinline__ void store_out(float* p, float v) { *p = v; }
static __device__ __forceinline__ void store_out(short* p, float v) { *p = f2bf(v); }

// ---------------- fp32 -> bf16 conversion (vectorized) ----------------
__global__ void cvt_f32_bf16(const float* __restrict__ in, short* __restrict__ out, int n) {
  int i = (blockIdx.x * blockDim.x + threadIdx.x) * 4;
  if (i >= n) return;
  float4 v = *reinterpret_cast<const float4*>(in + i);
  short4 o;
  o.x = f2bf(v.x); o.y = f2bf(v.y); o.z = f2bf(v.z); o.w = f2bf(v.w);
  *reinterpret_cast<short4*>(out + i) = o;
}

// ---------------- RoPE cos/sin table: [2048 pos][32 freq] ----------------
__global__ void rope_table_kernel(float2* __restrict__ tab) {
  int idx = blockIdx.x * blockDim.x + threadIdx.x;  // pos*32 + j
  int pos = idx >> 5, j = idx & 31;
  float freq = powf(10000.0f, -(float)j / 32.0f);   // theta^(-2j/64)
  float ang = (float)pos * freq;
  tab[idx] = make_float2(cosf(ang), sinf(ang));
}

// ---------------- RoPE apply in-place on bf16 [NR][DM] ----------------
__global__ void rope_apply_kernel(short* __restrict__ buf, const int* __restrict__ pos,
                                  const float2* __restrict__ tab) {
  int p = blockIdx.x * blockDim.x + threadIdx.x;  // [0, NR*512)
  int row = p >> 9, pr = p & 511;
  int h = pr >> 5, j = pr & 31;
  int col = h * 64 + 2 * j;
  short* q = buf + (size_t)row * DM + col;
  short2 v = *reinterpret_cast<short2*>(q);
  float2 cs = tab[pos[row] * 32 + j];
  float xe = bf2f(v.x), xo = bf2f(v.y);
  short2 o;
  o.x = f2bf(xe * cs.x - xo * cs.y);
  o.y = f2bf(xe * cs.y + xo * cs.x);
  *reinterpret_cast<short2*>(q) = o;
}

// ---------------- V transpose: V[b*S+s][h*64+d] -> Vt[(bh*64+d)][s] ----------------
// LDS tile with chunk-XOR swizzle -> conflict-free, both global sides coalesced.
__global__ __launch_bounds__(256) void vt_transpose_kernel(const short* __restrict__ V,
                                                           short* __restrict__ Vt) {
  __shared__ short tile[64][64];
  const int t = threadIdx.x;
  const int bh = blockIdx.y, b = bh >> 4, h = bh & 15;
  const int st = blockIdx.x * 64;
#pragma unroll
  for (int p = 0; p < 2; ++p) {
    int c = p * 256 + t;
    int srow = c >> 3, ch = c & 7;
    int chs = ch ^ ((srow >> 3) & 7);  // swizzle chunk index
    *reinterpret_cast<bf16x8*>(&tile[srow][chs * 8]) =
        *reinterpret_cast<const bf16x8*>(&V[(size_t)(b * SEQL + st + srow) * DM + h * 64 + ch * 8]);
  }
  __syncthreads();
#pragma unroll
  for (int p = 0; p < 2; ++p) {
    int c = p * 256 + t;
    int drow = c >> 3, soff = (c & 7) * 8;
    short o[8];
#pragma unroll
    for (int e = 0; e < 8; ++e) {
      int srow = soff + e;
      int col = (((drow >> 3) ^ ((srow >> 3) & 7)) << 3) + (drow & 7);
      o[e] = tile[srow][col];
    }
    *reinterpret_cast<bf16x8*>(&Vt[(size_t)(bh * DK + drow) * SEQL + st + soff]) =
        *reinterpret_cast<bf16x8*>(o);
  }
}

// ---------------- bf16 GEMM: C[M][N] = A[M][K] * B[N][K]^T ----------------
template <typename OutT>
static __device__ __forceinline__ void gemm_body(const short* __restrict__ A,
                                                 const short* __restrict__ B,
                                                 OutT* __restrict__ C,
                                                 int m0, int n0, int N, int K) {
  __shared__ short As[128][40];
  __shared__ short Bs[128][40];
  const int t = threadIdx.x;
  const int wid = t >> 6, lane = t & 63;
  const int wr = wid >> 1, wc = wid & 1;
  const int lrow = lane & 15, lk = lane >> 4;

  f32x4 acc[4][4];
#pragma unroll
  for (int i = 0; i < 4; ++i)
#pragma unroll
    for (int j = 0; j < 4; ++j) acc[i][j] = (f32x4){0.f, 0.f, 0.f, 0.f};

  for (int k0 = 0; k0 < K; k0 += 32) {
    __syncthreads();
#pragma unroll
    for (int p = 0; p < 2; ++p) {
      int c = p * 256 + t;
      int row = c >> 2, kc = (c & 3) * 8;
      *reinterpret_cast<bf16x8*>(&As[row][kc]) =
          *reinterpret_cast<const bf16x8*>(&A[(size_t)(m0 + row) * K + k0 + kc]);
      *reinterpret_cast<bf16x8*>(&Bs[row][kc]) =
          *reinterpret_cast<const bf16x8*>(&B[(size_t)(n0 + row) * K + k0 + kc]);
    }
    __syncthreads();
    bf16x8 af[4], bfr[4];
#pragma unroll
    for (int i = 0; i < 4; ++i) {
      af[i] = *reinterpret_cast<const bf16x8*>(&As[wr * 64 + i * 16 + lrow][lk * 8]);
      bfr[i] = *reinterpret_cast<const bf16x8*>(&Bs[wc * 64 + i * 16 + lrow][lk * 8]);
    }
#pragma unroll
    for (int i = 0; i < 4; ++i)
#pragma unroll
      for (int j = 0; j < 4; ++j)
        acc[i][j] = __builtin_amdgcn_mfma_f32_16x16x32_bf16(af[i], bfr[j], acc[i][j], 0, 0, 0);
  }
#pragma unroll
  for (int i = 0; i < 4; ++i)
#pragma unroll
    for (int j = 0; j < 4; ++j) {
      int row = m0 + wr * 64 + i * 16 + lk * 4;
      int col = n0 + wc * 64 + j * 16 + lrow;
#pragma unroll
      for (int r = 0; r < 4; ++r) store_out(&C[(size_t)(row + r) * N + col], acc[i][j][r]);
    }
}

__global__ __launch_bounds__(256) void qkv_gemm_kernel(
    const short* __restrict__ X, const short* __restrict__ Wq, const short* __restrict__ Wk,
    const short* __restrict__ Wv, short* __restrict__ Q, short* __restrict__ K,
    short* __restrict__ V) {
  int nb = blockIdx.x;
  const short* B = (nb < 8) ? Wq : (nb < 16) ? Wk : Wv;
  short* C = (nb < 8) ? Q : (nb < 16) ? K : V;
  gemm_body<short>(X, B, C, blockIdx.y * 128, (nb & 7) * 128, DM, DM);
}

__global__ __launch_bounds__(256) void out_gemm_kernel(const short* __restrict__ A,
                                                       const short* __restrict__ W,
                                                       float* __restrict__ C) {
  gemm_body<float>(A, W, C, blockIdx.y * 128, blockIdx.x * 128, DM, DM);
}

// ---------------- causal flash attention ----------------
// grid: (16, B*H). Each block does q-tiles {bx, 31-bx} -> uniform 33 kt-iterations.
// 4 waves/block, each wave owns 16 q rows. KBLK = 64. V pre-transposed (Vt[d][s]).
__global__ __launch_bounds__(256) void attn_kernel(const short* __restrict__ Q,
                                                   const short* __restrict__ K,
                                                   const short* __restrict__ Vt,
                                                   short* __restrict__ O) {
  __shared__ short Ks[64][72];        // K tile [k][d], +8 pad
  __shared__ short Vs[64][72];        // V^T tile [d][k], +8 pad
  __shared__ short Ps[4][16][72];     // per-wave P round-trip
  const int t = threadIdx.x;
  const int wid = t >> 6, lane = t & 63;
  const int lrow = lane & 15, lk = lane >> 4;
  const int bh = blockIdx.y;
  const int b = bh >> 4, h = bh & 15;
  const size_t base = (size_t)b * SEQL * DM + (size_t)h * DK;  // Q,K,O
  const size_t vbase = (size_t)bh * DK * SEQL;                 // Vt

  const int c0 = t, c1 = 256 + t;
  const int kr0 = c0 >> 3, ko0 = (c0 & 7) * 8;
  const int kr1 = c1 >> 3, ko1 = (c1 & 7) * 8;

#pragma unroll
  for (int pi = 0; pi < 2; ++pi) {
    const int qt = pi ? (31 - (int)blockIdx.x) : (int)blockIdx.x;

    bf16x8 aq[2];
    {
      int qrow = qt * 64 + wid * 16 + lrow;
#pragma unroll
      for (int c = 0; c < 2; ++c)
        aq[c] = *reinterpret_cast<const bf16x8*>(&Q[base + (size_t)qrow * DM + c * 32 + lk * 8]);
    }

    f32x4 oacc[4];
#pragma unroll
    for (int g = 0; g < 4; ++g) oacc[g] = (f32x4){0.f, 0.f, 0.f, 0.f};
    float mrow[4] = {-1e30f, -1e30f, -1e30f, -1e30f};
    float lsum[4] = {0.f, 0.f, 0.f, 0.f};
    const int qg0 = qt * 64 + wid * 16 + lk * 4;

    // prefetch kt=0 into registers (T14 async-stage split)
    bf16x8 kreg0, kreg1, vreg0, vreg1;
    kreg0 = *reinterpret_cast<const bf16x8*>(&K[base + (size_t)(kr0)*DM + ko0]);
    kreg1 = *reinterpret_cast<const bf16x8*>(&K[base + (size_t)(kr1)*DM + ko1]);
    vreg0 = *reinterpret_cast<const bf16x8*>(&Vt[vbase + (size_t)kr0 * SEQL + ko0]);
    vreg1 = *reinterpret_cast<const bf16x8*>(&Vt[vbase + (size_t)kr1 * SEQL + ko1]);

    for (int kt = 0; kt <= qt; ++kt) {
      __syncthreads();  // previous iteration's readers done with Ks/Vs
      *reinterpret_cast<bf16x8*>(&Ks[kr0][ko0]) = kreg0;
      *reinterpret_cast<bf16x8*>(&Ks[kr1][ko1]) = kreg1;
      *reinterpret_cast<bf16x8*>(&Vs[kr0][ko0]) = vreg0;
      *reinterpret_cast<bf16x8*>(&Vs[kr1][ko1]) = vreg1;
      if (kt < qt) {  // issue next tile's loads; latency hides under compute
        size_t koff = (size_t)(kt + 1) * 64;
        kreg0 = *reinterpret_cast<const bf16x8*>(&K[base + (koff + kr0) * DM + ko0]);
        kreg1 = *reinterpret_cast<const bf16x8*>(&K[base + (koff + kr1) * DM + ko1]);
        vreg0 = *reinterpret_cast<const bf16x8*>(&Vt[vbase + (size_t)kr0 * SEQL + koff + ko0]);
        vreg1 = *reinterpret_cast<const bf16x8*>(&Vt[vbase + (size_t)kr1 * SEQL + koff + ko1]);
      }
      __syncthreads();

      // S = Q K^T
      f32x4 s[4];
#pragma unroll
      for (int g = 0; g < 4; ++g) {
        bf16x8 b0 = *reinterpret_cast<const bf16x8*>(&Ks[g * 16 + lrow][lk * 8]);
        bf16x8 b1 = *reinterpret_cast<const bf16x8*>(&Ks[g * 16 + lrow][32 + lk * 8]);
        f32x4 z = (f32x4){0.f, 0.f, 0.f, 0.f};
        z = __builtin_amdgcn_mfma_f32_16x16x32_bf16(aq[0], b0, z, 0, 0, 0);
        s[g] = __builtin_amdgcn_mfma_f32_16x16x32_bf16(aq[1], b1, z, 0, 0, 0);
      }

      const bool diag = (kt == qt);
#pragma unroll
      for (int g = 0; g < 4; ++g)
#pragma unroll
        for (int r = 0; r < 4; ++r) {
          float v = s[g][r] * 0.125f;  // 1/sqrt(64)
          if (diag && (kt * 64 + g * 16 + lrow) > (qg0 + r)) v = -1e30f;
          s[g][r] = v;
        }

      // online softmax across the 16 lanes sharing lk
      float pv[4][4];
#pragma unroll
      for (int r = 0; r < 4; ++r) {
        float mx = fmaxf(fmaxf(s[0][r], s[1][r]), fmaxf(s[2][r], s[3][r]));
#pragma unroll
        for (int off = 1; off < 16; off <<= 1) mx = fmaxf(mx, __shfl_xor(mx, off));
        float mnew = fmaxf(mrow[r], mx);
        float alpha = __expf(mrow[r] - mnew);
        float psum = 0.f;
#pragma unroll
        for (int g = 0; g < 4; ++g) {
          float p = __expf(s[g][r] - mnew);
          pv[g][r] = p;
          psum += p;
        }
#pragma unroll
        for (int off = 1; off < 16; off <<= 1) psum += __shfl_xor(psum, off);
        lsum[r] = lsum[r] * alpha + psum;
        mrow[r] = mnew;
#pragma unroll
        for (int g = 0; g < 4; ++g) oacc[g][r] *= alpha;
      }

      // P round-trip through per-wave LDS slice (wave-local: no __syncthreads needed,
      // DS ops are wave-ordered; drain lgkm then fence the scheduler)
#pragma unroll
      for (int g = 0; g < 4; ++g)
#pragma unroll
        for (int r = 0; r < 4; ++r) Ps[wid][lk * 4 + r][g * 16 + lrow] = f2bf(pv[g][r]);
      asm volatile("s_waitcnt lgkmcnt(0)" ::: "memory");
      __builtin_amdgcn_sched_barrier(0);

      bf16x8 pa[2];
#pragma unroll
      for (int c = 0; c < 2; ++c)
        pa[c] = *reinterpret_cast<const bf16x8*>(&Ps[wid][lrow][c * 32 + lk * 8]);
#pragma unroll
      for (int g = 0; g < 4; ++g) {
        bf16x8 v0 = *reinterpret_cast<const bf16x8*>(&Vs[g * 16 + lrow][lk * 8]);
        bf16x8 v1 = *reinterpret_cast<const bf16x8*>(&Vs[g * 16 + lrow][32 + lk * 8]);
        oacc[g] = __builtin_amdgcn_mfma_f32_16x16x32_bf16(pa[0], v0, oacc[g], 0, 0, 0);
        oacc[g] = __builtin_amdgcn_mfma_f32_16x16x32_bf16(pa[1], v1, oacc[g], 0, 0, 0);
      }
    }

#pragma unroll
    for (int g = 0; g < 4; ++g)
#pragma unroll
      for (int r = 0; r < 4; ++r) {
        float v = oacc[g][r] / lsum[r];
        O[base + (size_t)(qt * 64 + wid * 16 + lk * 4 + r) * DM + g * 16 + lrow] = f2bf(v);
      }
  }
}

// ---------------- host launch ----------------
extern "C" void kernel_launch(void* const* d_in, const int* in_sizes, int n_in,
                              void* d_out, int out_size, void* d_ws, size_t ws_size,
                              hipStream_t stream) {
  const float* x = (const float*)d_in[0];
  const float* wq = (const float*)d_in[1];
  const float* wk = (const float*)d_in[2];
  const float* wv = (const float*)d_in[3];
  const float* wo = (const float*)d_in[4];
  const int* tpos = (const int*)d_in[5];
  float* out = (float*)d_out;

  char* w = (char*)d_ws;
  short* xb = (short*)w;  w += (size_t)NR * DM * 2;
  short* wqb = (short*)w; w += (size_t)DM * DM * 2;
  short* wkb = (short*)w; w += (size_t)DM * DM * 2;
  short* wvb = (short*)w; w += (size_t)DM * DM * 2;
  short* wob = (short*)w; w += (size_t)DM * DM * 2;
  short* Qb = (short*)w;  w += (size_t)NR * DM * 2;
  short* Kb = (short*)w;  w += (size_t)NR * DM * 2;
  short* Vb = (short*)w;  w += (size_t)NR * DM * 2;
  short* Ob = (short*)w;  w += (size_t)NR * DM * 2;
  float2* tab = (float2*)w;
  short* Vtb = xb;  // alias: xb's last use is qkv_gemm, Vt produced after

  cvt_f32_bf16<<<NR * DM / 1024, 256, 0, stream>>>(x, xb, NR * DM);
  cvt_f32_bf16<<<DM * DM / 1024, 256, 0, stream>>>(wq, wqb, DM * DM);
  cvt_f32_bf16<<<DM * DM / 1024, 256, 0, stream>>>(wk, wkb, DM * DM);
  cvt_f32_bf16<<<DM * DM / 1024, 256, 0, stream>>>(wv, wvb, DM * DM);
  cvt_f32_bf16<<<DM * DM / 1024, 256, 0, stream>>>(wo, wob, DM * DM);
  rope_table_kernel<<<2048 * 32 / 256, 256, 0, stream>>>(tab);
  qkv_gemm_kernel<<<dim3(24, NR / 128), 256, 0, stream>>>(xb, wqb, wkb, wvb, Qb, Kb, Vb);
  rope_apply_kernel<<<NR * 512 / 256, 256, 0, stream>>>(Qb, tpos, tab);
  rope_apply_kernel<<<NR * 512 / 256, 256, 0, stream>>>(Kb, tpos, tab);
  vt_transpose_kernel<<<dim3(SEQL / 64, NB * NH), 256, 0, stream>>>(Vb, Vtb);
  attn_kernel<<<dim3(16, NB * NH), 256, 0, stream>>>(Qb, Kb, Vtb, Ob);
  out_gemm_kernel<<<dim3(DM / 128, NR / 128), 256, 0, stream>>>(Ob, wob, out);
}

// Round 3
// 149.473 us; speedup vs baseline: 2.0068x; 1.1215x over previous
//
#include <hip/hip_runtime.h>
#include <cstdint>
#include <cstddef>

#define NH 16
#define DK 64
#define DM 1024
#define SEQL 2048
#define NB 2
#define NR (NB * SEQL)   // 4096 token rows

typedef short bf16x8 __attribute__((ext_vector_type(8)));
typedef float f32x4 __attribute__((ext_vector_type(4)));

static __device__ __forceinline__ float bf2f(short u) {
  union { unsigned int i; float f; } x;
  x.i = ((unsigned int)(unsigned short)u) << 16;
  return x.f;
}
static __device__ __forceinline__ short f2bf(float f) {
  union { unsigned int i; float f; } x;
  x.f = f;
  unsigned int r = x.i + 0x7fffu + ((x.i >> 16) & 1u);  // RNE
  return (short)(r >> 16);
}
static __device__ __forceinline__ unsigned pk2(float a, float b) {
  return ((unsigned)(unsigned short)f2bf(b) << 16) | (unsigned)(unsigned short)f2bf(a);
}

static __device__ __forceinline__ void store_out(float* p, float v) { *p = v; }
static __device__ __forceinline__ void store_out(short* p, float v) { *p = f2bf(v); }

// async global->LDS, 16B per lane; lds base must be wave-uniform (HW adds lane*16)
static __device__ __forceinline__ void gload16(const short* g, short* l) {
  __builtin_amdgcn_global_load_lds((const __attribute__((address_space(1))) void*)g,
                                   (__attribute__((address_space(3))) void*)l, 16, 0, 0);
}

// ---------------- fp32 -> bf16 conversion ----------------
__global__ void cvt_f32_bf16(const float* __restrict__ in, short* __restrict__ out, int n) {
  int i = (blockIdx.x * blockDim.x + threadIdx.x) * 4;
  if (i >= n) return;
  float4 v = *reinterpret_cast<const float4*>(in + i);
  short4 o;
  o.x = f2bf(v.x); o.y = f2bf(v.y); o.z = f2bf(v.z); o.w = f2bf(v.w);
  *reinterpret_cast<short4*>(out + i) = o;
}

// 4 weight matrices in one launch: grid (DM*DM/1024, 4)
__global__ void cvt_w4(const float* __restrict__ w0, const float* __restrict__ w1,
                       const float* __restrict__ w2, const float* __restrict__ w3,
                       short* __restrict__ o0, short* __restrict__ o1,
                       short* __restrict__ o2, short* __restrict__ o3) {
  int y = blockIdx.y;
  const float* in = (y == 0) ? w0 : (y == 1) ? w1 : (y == 2) ? w2 : w3;
  short* out = (y == 0) ? o0 : (y == 1) ? o1 : (y == 2) ? o2 : o3;
  int i = (blockIdx.x * blockDim.x + threadIdx.x) * 4;
  float4 v = *reinterpret_cast<const float4*>(in + i);
  short4 o;
  o.x = f2bf(v.x); o.y = f2bf(v.y); o.z = f2bf(v.z); o.w = f2bf(v.w);
  *reinterpret_cast<short4*>(out + i) = o;
}

// ---------------- RoPE cos/sin table: [2048 pos][32 freq] ----------------
__global__ void rope_table_kernel(float2* __restrict__ tab) {
  int idx = blockIdx.x * blockDim.x + threadIdx.x;  // pos*32 + j
  int pos = idx >> 5, j = idx & 31;
  float freq = powf(10000.0f, -(float)j / 32.0f);   // theta^(-2j/64)
  float ang = (float)pos * freq;
  tab[idx] = make_float2(cosf(ang), sinf(ang));
}

// ---------------- RoPE apply in-place on bf16 [NR][DM], Q and K fused ----------------
__global__ void rope_apply_kernel(short* __restrict__ Qb, short* __restrict__ Kb,
                                  const int* __restrict__ pos, const float2* __restrict__ tab) {
  short* buf = blockIdx.y ? Kb : Qb;
  int p = blockIdx.x * blockDim.x + threadIdx.x;  // [0, NR*512)
  int row = p >> 9, pr = p & 511;
  int h = pr >> 5, j = pr & 31;
  int col = h * 64 + 2 * j;
  short* q = buf + (size_t)row * DM + col;
  short2 v = *reinterpret_cast<short2*>(q);
  float2 cs = tab[pos[row] * 32 + j];
  float xe = bf2f(v.x), xo = bf2f(v.y);
  short2 o;
  o.x = f2bf(xe * cs.x - xo * cs.y);
  o.y = f2bf(xe * cs.y + xo * cs.x);
  *reinterpret_cast<short2*>(q) = o;
}

// ---------------- V transpose: V[b*S+s][h*64+d] -> Vt[(bh*64+d)][s] ----------------
__global__ __launch_bounds__(256) void vt_transpose_kernel(const short* __restrict__ V,
                                                           short* __restrict__ Vt) {
  __shared__ short tile[64][64];
  const int t = threadIdx.x;
  const int bh = blockIdx.y, b = bh >> 4, h = bh & 15;
  const int st = blockIdx.x * 64;
#pragma unroll
  for (int p = 0; p < 2; ++p) {
    int c = p * 256 + t;
    int srow = c >> 3, ch = c & 7;
    int chs = ch ^ ((srow >> 3) & 7);  // swizzle chunk index
    *reinterpret_cast<bf16x8*>(&tile[srow][chs * 8]) =
        *reinterpret_cast<const bf16x8*>(&V[(size_t)(b * SEQL + st + srow) * DM + h * 64 + ch * 8]);
  }
  __syncthreads();
#pragma unroll
  for (int p = 0; p < 2; ++p) {
    int c = p * 256 + t;
    int drow = c >> 3, soff = (c & 7) * 8;
    short o[8];
#pragma unroll
    for (int e = 0; e < 8; ++e) {
      int srow = soff + e;
      int col = (((drow >> 3) ^ ((srow >> 3) & 7)) << 3) + (drow & 7);
      o[e] = tile[srow][col];
    }
    *reinterpret_cast<bf16x8*>(&Vt[(size_t)(bh * DK + drow) * SEQL + st + soff]) =
        *reinterpret_cast<bf16x8*>(o);
  }
}

// ---------------- bf16 GEMM (m97 structure): C[M][N] = A[M][K] * B[N][K]^T ----------------
// 128x128 tile, BK=32, 4 waves, global_load_lds width-16 staging, linear LDS.
template <typename OutT>
static __device__ __forceinline__ void gemm_body(const short* __restrict__ A,
                                                 const short* __restrict__ B,
                                                 OutT* __restrict__ C,
                                                 int m0, int n0, int N, int K) {
  __shared__ short As[128][32];
  __shared__ short Bs[128][32];
  const int t = threadIdx.x;
  const int wid = t >> 6, lane = t & 63;
  const int wr = wid >> 1, wc = wid & 1;
  const int lrow = lane & 15, lk = lane >> 4;

  f32x4 acc[4][4];
#pragma unroll
  for (int i = 0; i < 4; ++i)
#pragma unroll
    for (int j = 0; j < 4; ++j) acc[i][j] = (f32x4){0.f, 0.f, 0.f, 0.f};

  for (int k0 = 0; k0 < K; k0 += 32) {
    __syncthreads();  // prev tile's readers done
#pragma unroll
    for (int p = 0; p < 2; ++p) {
      int c = p * 256 + t;            // 512 chunks of 8 bf16 = 128x32
      int row = c >> 2, kc = (c & 3) * 8;
      gload16(&A[(size_t)(m0 + row) * K + k0 + kc], &As[0][0] + (size_t)(p * 256 + wid * 64) * 8);
      gload16(&B[(size_t)(n0 + row) * K + k0 + kc], &Bs[0][0] + (size_t)(p * 256 + wid * 64) * 8);
    }
    __syncthreads();  // drains vmcnt -> LDS ready
    bf16x8 af[4], bfr[4];
#pragma unroll
    for (int i = 0; i < 4; ++i) {
      af[i] = *reinterpret_cast<const bf16x8*>(&As[wr * 64 + i * 16 + lrow][lk * 8]);
      bfr[i] = *reinterpret_cast<const bf16x8*>(&Bs[wc * 64 + i * 16 + lrow][lk * 8]);
    }
    __builtin_amdgcn_s_setprio(1);
#pragma unroll
    for (int i = 0; i < 4; ++i)
#pragma unroll
      for (int j = 0; j < 4; ++j)
        acc[i][j] = __builtin_amdgcn_mfma_f32_16x16x32_bf16(af[i], bfr[j], acc[i][j], 0, 0, 0);
    __builtin_amdgcn_s_setprio(0);
  }
#pragma unroll
  for (int i = 0; i < 4; ++i)
#pragma unroll
    for (int j = 0; j < 4; ++j) {
      int row = m0 + wr * 64 + i * 16 + lk * 4;
      int col = n0 + wc * 64 + j * 16 + lrow;
#pragma unroll
      for (int r = 0; r < 4; ++r) store_out(&C[(size_t)(row + r) * N + col], acc[i][j][r]);
    }
}

__global__ __launch_bounds__(256) void qkv_gemm_kernel(
    const short* __restrict__ X, const short* __restrict__ Wq, const short* __restrict__ Wk,
    const short* __restrict__ Wv, short* __restrict__ Q, short* __restrict__ K,
    short* __restrict__ V) {
  int nb = blockIdx.x;
  const short* B = (nb < 8) ? Wq : (nb < 16) ? Wk : Wv;
  short* C = (nb < 8) ? Q : (nb < 16) ? K : V;
  gemm_body<short>(X, B, C, blockIdx.y * 128, (nb & 7) * 128, DM, DM);
}

__global__ __launch_bounds__(256) void out_gemm_kernel(const short* __restrict__ A,
                                                       const short* __restrict__ W,
                                                       float* __restrict__ C) {
  gemm_body<float>(A, W, C, blockIdx.y * 128, blockIdx.x * 128, DM, DM);
}

// ---------------- causal flash attention, swapped-QK^T, lane-local softmax ----------------
// grid: (8, B*H), 512 threads (8 waves). Each block: q-tiles {bx, 15-bx} of 128 rows
// (uniform 36 kt-iterations). Wave w owns q rows [qt*128+w*16, +16). KBLK=64.
// S^T = mfma(K_frag, Q_frag): lane (lrow,lk) holds S[q=qmin+lrow][k=kt*64+g*16+lk*4+r].
// Softmax per lane-row: local max + 2 shfl_xor. PV: P->Ps (per-wave LDS) -> A-frag.
__global__ __launch_bounds__(512) void attn_kernel(const short* __restrict__ Q,
                                                   const short* __restrict__ K,
                                                   const short* __restrict__ Vt,
                                                   short* __restrict__ O) {
  __shared__ short Ks[2][64][72];   // [buf][k][d], 144B rows (16B-aligned), conflict-free b128
  __shared__ short Vs[2][64][72];   // [buf][d][k]
  __shared__ short Ps[8][16][72];   // per-wave P exchange [q][k]
  const int t = threadIdx.x;
  const int wid = t >> 6, lane = t & 63;
  const int lrow = lane & 15, lk = lane >> 4;
  const int bh = blockIdx.y, b = bh >> 4, h = bh & 15;
  const size_t base = (size_t)b * SEQL * DM + (size_t)h * DK;  // Q,K,O
  const size_t vbase = (size_t)bh * DK * SEQL;                 // Vt
  const int tr = t >> 3, to = (t & 7) * 8;                     // staging coords (64x64 tile)

#pragma unroll
  for (int pi = 0; pi < 2; ++pi) {
    const int qt = pi ? (15 - (int)blockIdx.x) : (int)blockIdx.x;
    const int ktmax = 2 * qt + 1;
    const int qmin = qt * 128 + wid * 16;

    bf16x8 aq[2];
#pragma unroll
    for (int c = 0; c < 2; ++c)
      aq[c] = *reinterpret_cast<const bf16x8*>(
          &Q[base + (size_t)(qmin + lrow) * DM + c * 32 + lk * 8]);

    f32x4 oacc[4];
#pragma unroll
    for (int g = 0; g < 4; ++g) oacc[g] = (f32x4){0.f, 0.f, 0.f, 0.f};
    float mrow = -1e30f, lsum = 0.f;  // per lane: q-row = qmin + lrow

    __syncthreads();  // guard buffer reuse across passes
    // stage tile 0 into buf 0
    {
      bf16x8 k0 = *reinterpret_cast<const bf16x8*>(&K[base + (size_t)tr * DM + to]);
      bf16x8 v0 = *reinterpret_cast<const bf16x8*>(&Vt[vbase + (size_t)tr * SEQL + to]);
      *reinterpret_cast<bf16x8*>(&Ks[0][tr][to]) = k0;
      *reinterpret_cast<bf16x8*>(&Vs[0][tr][to]) = v0;
    }
    int cur = 0;
    bf16x8 kreg, vreg;
    for (int kt = 0; kt <= ktmax; ++kt) {
      __syncthreads();  // buf[cur] ready
      if (kt < ktmax) {  // issue next tile's loads; latency hides under compute
        size_t ko = (size_t)(kt + 1) * 64;
        kreg = *reinterpret_cast<const bf16x8*>(&K[base + (ko + tr) * DM + to]);
        vreg = *reinterpret_cast<const bf16x8*>(&Vt[vbase + (size_t)tr * SEQL + ko + to]);
      }
      const bool active = (kt * 64 <= qmin + 15);  // wave-uniform
      if (active) {
        // S^T = K Q^T
        f32x4 st[4];
        __builtin_amdgcn_s_setprio(1);
#pragma unroll
        for (int g = 0; g < 4; ++g) {
          bf16x8 kf0 = *reinterpret_cast<const bf16x8*>(&Ks[cur][g * 16 + lrow][lk * 8]);
          bf16x8 kf1 = *reinterpret_cast<const bf16x8*>(&Ks[cur][g * 16 + lrow][32 + lk * 8]);
          f32x4 z = (f32x4){0.f, 0.f, 0.f, 0.f};
          z = __builtin_amdgcn_mfma_f32_16x16x32_bf16(kf0, aq[0], z, 0, 0, 0);
          st[g] = __builtin_amdgcn_mfma_f32_16x16x32_bf16(kf1, aq[1], z, 0, 0, 0);
        }
        __builtin_amdgcn_s_setprio(0);
        const int qg = qmin + lrow;  // this lane's q row
#pragma unroll
        for (int g = 0; g < 4; ++g)
#pragma unroll
          for (int r = 0; r < 4; ++r) st[g][r] *= 0.125f;  // 1/sqrt(64)
        if (kt * 64 + 63 > qmin) {   // mask tile (wave-uniform branch)
#pragma unroll
          for (int g = 0; g < 4; ++g)
#pragma unroll
            for (int r = 0; r < 4; ++r)
              if (kt * 64 + g * 16 + lk * 4 + r > qg) st[g][r] = -1e30f;
        }
        // lane-local softmax for q-row qg
        float mx = -1e30f;
#pragma unroll
        for (int g = 0; g < 4; ++g)
#pragma unroll
          for (int r = 0; r < 4; ++r) mx = fmaxf(mx, st[g][r]);
        mx = fmaxf(mx, __shfl_xor(mx, 16));
        mx = fmaxf(mx, __shfl_xor(mx, 32));
        float mnew = fmaxf(mrow, mx);
        float alpha = __expf(mrow - mnew);
        float p[4][4], psum = 0.f;
#pragma unroll
        for (int g = 0; g < 4; ++g)
#pragma unroll
          for (int r = 0; r < 4; ++r) {
            float e = __expf(st[g][r] - mnew);
            p[g][r] = e;
            psum += e;
          }
        psum += __shfl_xor(psum, 16);
        psum += __shfl_xor(psum, 32);
        lsum = lsum * alpha + psum;
        mrow = mnew;
        // P -> per-wave LDS (row q=lrow, cols k_local), b64 writes
#pragma unroll
        for (int g = 0; g < 4; ++g) {
          uint2 wv = make_uint2(pk2(p[g][0], p[g][1]), pk2(p[g][2], p[g][3]));
          *reinterpret_cast<uint2*>(&Ps[wid][lrow][g * 16 + lk * 4]) = wv;
        }
        asm volatile("s_waitcnt lgkmcnt(0)" ::: "memory");
        __builtin_amdgcn_sched_barrier(0);
        bf16x8 pa0 = *reinterpret_cast<const bf16x8*>(&Ps[wid][lrow][lk * 8]);
        bf16x8 pa1 = *reinterpret_cast<const bf16x8*>(&Ps[wid][lrow][32 + lk * 8]);
        // broadcast alpha to the accumulator layout (row = lk*4+r)
        float alr[4];
#pragma unroll
        for (int r = 0; r < 4; ++r) alr[r] = __shfl(alpha, lk * 4 + r);
#pragma unroll
        for (int g = 0; g < 4; ++g)
#pragma unroll
          for (int r = 0; r < 4; ++r) oacc[g][r] *= alr[r];
        __builtin_amdgcn_s_setprio(1);
#pragma unroll
        for (int g = 0; g < 4; ++g) {
          bf16x8 vf0 = *reinterpret_cast<const bf16x8*>(&Vs[cur][g * 16 + lrow][lk * 8]);
          bf16x8 vf1 = *reinterpret_cast<const bf16x8*>(&Vs[cur][g * 16 + lrow][32 + lk * 8]);
          oacc[g] = __builtin_amdgcn_mfma_f32_16x16x32_bf16(pa0, vf0, oacc[g], 0, 0, 0);
          oacc[g] = __builtin_amdgcn_mfma_f32_16x16x32_bf16(pa1, vf1, oacc[g], 0, 0, 0);
        }
        __builtin_amdgcn_s_setprio(0);
      }
      if (kt < ktmax) {  // write next tile at iteration tail (T14)
        *reinterpret_cast<bf16x8*>(&Ks[cur ^ 1][tr][to]) = kreg;
        *reinterpret_cast<bf16x8*>(&Vs[cur ^ 1][tr][to]) = vreg;
      }
      cur ^= 1;
    }
    // epilogue: normalize (lsum lives at lane lrow=q; acc rows are lk*4+r)
    float lr[4];
#pragma unroll
    for (int r = 0; r < 4; ++r) lr[r] = __shfl(lsum, lk * 4 + r);
#pragma unroll
    for (int g = 0; g < 4; ++g)
#pragma unroll
      for (int r = 0; r < 4; ++r) {
        float v = oacc[g][r] / lr[r];
        O[base + (size_t)(qmin + lk * 4 + r) * DM + g * 16 + lrow] = f2bf(v);
      }
  }
}

// ---------------- host launch ----------------
extern "C" void kernel_launch(void* const* d_in, const int* in_sizes, int n_in,
                              void* d_out, int out_size, void* d_ws, size_t ws_size,
                              hipStream_t stream) {
  const float* x = (const float*)d_in[0];
  const float* wq = (const float*)d_in[1];
  const float* wk = (const float*)d_in[2];
  const float* wv = (const float*)d_in[3];
  const float* wo = (const float*)d_in[4];
  const int* tpos = (const int*)d_in[5];
  float* out = (float*)d_out;

  char* w = (char*)d_ws;
  short* xb = (short*)w;  w += (size_t)NR * DM * 2;
  short* wqb = (short*)w; w += (size_t)DM * DM * 2;
  short* wkb = (short*)w; w += (size_t)DM * DM * 2;
  short* wvb = (short*)w; w += (size_t)DM * DM * 2;
  short* wob = (short*)w; w += (size_t)DM * DM * 2;
  short* Qb = (short*)w;  w += (size_t)NR * DM * 2;
  short* Kb = (short*)w;  w += (size_t)NR * DM * 2;
  short* Vb = (short*)w;  w += (size_t)NR * DM * 2;
  short* Ob = (short*)w;  w += (size_t)NR * DM * 2;
  float2* tab = (float2*)w;
  short* Vtb = xb;  // alias: xb's last use is qkv_gemm; Vt produced after

  cvt_f32_bf16<<<NR * DM / 1024, 256, 0, stream>>>(x, xb, NR * DM);
  cvt_w4<<<dim3(DM * DM / 1024, 4), 256, 0, stream>>>(wq, wk, wv, wo, wqb, wkb, wvb, wob);
  rope_table_kernel<<<2048 * 32 / 256, 256, 0, stream>>>(tab);
  qkv_gemm_kernel<<<dim3(24, NR / 128), 256, 0, stream>>>(xb, wqb, wkb, wvb, Qb, Kb, Vb);
  rope_apply_kernel<<<dim3(NR * 512 / 256, 2), 256, 0, stream>>>(Qb, Kb, tpos, tab);
  vt_transpose_kernel<<<dim3(SEQL / 64, NB * NH), 256, 0, stream>>>(Vb, Vtb);
  attn_kernel<<<dim3(8, NB * NH), 512, 0, stream>>>(Qb, Kb, Vtb, Ob);
  out_gemm_kernel<<<dim3(DM / 128, NR / 128), 256, 0, stream>>>(Ob, wob, out);
}

// Round 4
// 136.206 us; speedup vs baseline: 2.2023x; 1.0974x over previous
//
#include <hip/hip_runtime.h>
#include <cstdint>
#include <cstddef>

#define NH 16
#define DK 64
#define DM 1024
#define SEQL 2048
#define NB 2
#define NR (NB * SEQL)   // 4096 token rows

typedef short bf16x8 __attribute__((ext_vector_type(8)));
typedef float f32x4 __attribute__((ext_vector_type(4)));

static __device__ __forceinline__ float bf2f(short u) {
  union { unsigned int i; float f; } x;
  x.i = ((unsigned int)(unsigned short)u) << 16;
  return x.f;
}
static __device__ __forceinline__ short f2bf(float f) {
  union { unsigned int i; float f; } x;
  x.f = f;
  unsigned int r = x.i + 0x7fffu + ((x.i >> 16) & 1u);  // RNE
  return (short)(r >> 16);
}
static __device__ __forceinline__ unsigned pk2(float a, float b) {
  return ((unsigned)(unsigned short)f2bf(b) << 16) | (unsigned)(unsigned short)f2bf(a);
}

static __device__ __forceinline__ void store_out(float* p, float v) { *p = v; }
static __device__ __forceinline__ void store_out(short* p, float v) { *p = f2bf(v); }

// async global->LDS, 16B per lane; lds base wave-uniform (HW adds lane*16)
static __device__ __forceinline__ void gload16(const short* g, short* l) {
  __builtin_amdgcn_global_load_lds((const __attribute__((address_space(1))) void*)g,
                                   (__attribute__((address_space(3))) void*)l, 16, 0, 0);
}

// ---------------- all fp32 -> bf16 converts in one launch ----------------
// grid (DM*DM/1024, 8): y<4 -> x slices, y>=4 -> weights
__global__ void cvt_all(const float* __restrict__ x, const float* __restrict__ w0,
                        const float* __restrict__ w1, const float* __restrict__ w2,
                        const float* __restrict__ w3, short* __restrict__ xb,
                        short* __restrict__ o0, short* __restrict__ o1,
                        short* __restrict__ o2, short* __restrict__ o3) {
  int y = blockIdx.y;
  const float* in;
  short* out;
  if (y < 4) { in = x + (size_t)y * DM * DM; out = xb + (size_t)y * DM * DM; }
  else if (y == 4) { in = w0; out = o0; }
  else if (y == 5) { in = w1; out = o1; }
  else if (y == 6) { in = w2; out = o2; }
  else { in = w3; out = o3; }
  int i = (blockIdx.x * blockDim.x + threadIdx.x) * 4;
  float4 v = *reinterpret_cast<const float4*>(in + i);
  short4 o;
  o.x = f2bf(v.x); o.y = f2bf(v.y); o.z = f2bf(v.z); o.w = f2bf(v.w);
  *reinterpret_cast<short4*>(out + i) = o;
}

// ---------------- RoPE cos/sin table: [2048 pos][32 freq] ----------------
__global__ void rope_table_kernel(float2* __restrict__ tab) {
  int idx = blockIdx.x * blockDim.x + threadIdx.x;  // pos*32 + j
  int pos = idx >> 5, j = idx & 31;
  float freq = powf(10000.0f, -(float)j / 32.0f);   // theta^(-2j/64)
  float ang = (float)pos * freq;
  tab[idx] = make_float2(cosf(ang), sinf(ang));
}

// ---------------- RoPE apply, vectorized bf16x8 (4 pairs/thread) ----------------
// Q additionally pre-scaled by 0.125*log2(e) (softmax works in exp2 domain).
__global__ void rope_apply_kernel(short* __restrict__ Qb, short* __restrict__ Kb,
                                  const int* __restrict__ pos, const float2* __restrict__ tab) {
  short* buf = blockIdx.y ? Kb : Qb;
  const float scale = blockIdx.y ? 1.0f : 0.1803368801f;  // 0.125*log2e
  int gid = blockIdx.x * blockDim.x + threadIdx.x;        // [0, NR*DM/8)
  int elem = gid * 8;
  int row = elem >> 10, off = elem & 1023;
  int j0 = (off & 63) >> 1;
  short* ptr = buf + (size_t)row * DM + off;
  bf16x8 v = *reinterpret_cast<bf16x8*>(ptr);
  const float2* tp = &tab[pos[row] * 32 + j0];
  bf16x8 o;
#pragma unroll
  for (int q = 0; q < 4; ++q) {
    float2 cs = tp[q];
    float xe = bf2f(v[2 * q]), xo = bf2f(v[2 * q + 1]);
    o[2 * q] = f2bf((xe * cs.x - xo * cs.y) * scale);
    o[2 * q + 1] = f2bf((xe * cs.y + xo * cs.x) * scale);
  }
  *reinterpret_cast<bf16x8*>(ptr) = o;
}

// ---------------- V transpose: V[b*S+s][h*64+d] -> Vt[(bh*64+d)][s] ----------------
__global__ __launch_bounds__(256) void vt_transpose_kernel(const short* __restrict__ V,
                                                           short* __restrict__ Vt) {
  __shared__ short tile[64][64];
  const int t = threadIdx.x;
  const int bh = blockIdx.y, b = bh >> 4, h = bh & 15;
  const int st = blockIdx.x * 64;
#pragma unroll
  for (int p = 0; p < 2; ++p) {
    int c = p * 256 + t;
    int srow = c >> 3, ch = c & 7;
    int chs = ch ^ ((srow >> 3) & 7);  // swizzle chunk index
    *reinterpret_cast<bf16x8*>(&tile[srow][chs * 8]) =
        *reinterpret_cast<const bf16x8*>(&V[(size_t)(b * SEQL + st + srow) * DM + h * 64 + ch * 8]);
  }
  __syncthreads();
#pragma unroll
  for (int p = 0; p < 2; ++p) {
    int c = p * 256 + t;
    int drow = c >> 3, soff = (c & 7) * 8;
    short o[8];
#pragma unroll
    for (int e = 0; e < 8; ++e) {
      int srow = soff + e;
      int col = (((drow >> 3) ^ ((srow >> 3) & 7)) << 3) + (drow & 7);
      o[e] = tile[srow][col];
    }
    *reinterpret_cast<bf16x8*>(&Vt[(size_t)(bh * DK + drow) * SEQL + st + soff]) =
        *reinterpret_cast<bf16x8*>(o);
  }
}

// ---------------- bf16 GEMM (m97 structure): C[M][N] = A[M][K] * B[N][K]^T ----------------
template <typename OutT>
static __device__ __forceinline__ void gemm_body(const short* __restrict__ A,
                                                 const short* __restrict__ B,
                                                 OutT* __restrict__ C,
                                                 int m0, int n0, int N, int K) {
  __shared__ short As[128][32];
  __shared__ short Bs[128][32];
  const int t = threadIdx.x;
  const int wid = t >> 6, lane = t & 63;
  const int wr = wid >> 1, wc = wid & 1;
  const int lrow = lane & 15, lk = lane >> 4;

  f32x4 acc[4][4];
#pragma unroll
  for (int i = 0; i < 4; ++i)
#pragma unroll
    for (int j = 0; j < 4; ++j) acc[i][j] = (f32x4){0.f, 0.f, 0.f, 0.f};

  for (int k0 = 0; k0 < K; k0 += 32) {
    __syncthreads();
#pragma unroll
    for (int p = 0; p < 2; ++p) {
      int c = p * 256 + t;
      int row = c >> 2, kc = (c & 3) * 8;
      gload16(&A[(size_t)(m0 + row) * K + k0 + kc], &As[0][0] + (size_t)(p * 256 + wid * 64) * 8);
      gload16(&B[(size_t)(n0 + row) * K + k0 + kc], &Bs[0][0] + (size_t)(p * 256 + wid * 64) * 8);
    }
    __syncthreads();
    bf16x8 af[4], bfr[4];
#pragma unroll
    for (int i = 0; i < 4; ++i) {
      af[i] = *reinterpret_cast<const bf16x8*>(&As[wr * 64 + i * 16 + lrow][lk * 8]);
      bfr[i] = *reinterpret_cast<const bf16x8*>(&Bs[wc * 64 + i * 16 + lrow][lk * 8]);
    }
    __builtin_amdgcn_s_setprio(1);
#pragma unroll
    for (int i = 0; i < 4; ++i)
#pragma unroll
      for (int j = 0; j < 4; ++j)
        acc[i][j] = __builtin_amdgcn_mfma_f32_16x16x32_bf16(af[i], bfr[j], acc[i][j], 0, 0, 0);
    __builtin_amdgcn_s_setprio(0);
  }
#pragma unroll
  for (int i = 0; i < 4; ++i)
#pragma unroll
    for (int j = 0; j < 4; ++j) {
      int row = m0 + wr * 64 + i * 16 + lk * 4;
      int col = n0 + wc * 64 + j * 16 + lrow;
#pragma unroll
      for (int r = 0; r < 4; ++r) store_out(&C[(size_t)(row + r) * N + col], acc[i][j][r]);
    }
}

__global__ __launch_bounds__(256) void qkv_gemm_kernel(
    const short* __restrict__ X, const short* __restrict__ Wq, const short* __restrict__ Wk,
    const short* __restrict__ Wv, short* __restrict__ Q, short* __restrict__ K,
    short* __restrict__ V) {
  int nb = blockIdx.x;
  const short* B = (nb < 8) ? Wq : (nb < 16) ? Wk : Wv;
  short* C = (nb < 8) ? Q : (nb < 16) ? K : V;
  gemm_body<short>(X, B, C, blockIdx.y * 128, (nb & 7) * 128, DM, DM);
}

__global__ __launch_bounds__(256) void out_gemm_kernel(const short* __restrict__ A,
                                                       const short* __restrict__ W,
                                                       float* __restrict__ C) {
  gemm_body<float>(A, W, C, blockIdx.y * 128, blockIdx.x * 128, DM, DM);
}

// ---------------- causal flash attention ----------------
// grid (16, 32), 256 thr (4 waves). XCD-swizzled (bh,bx); block does q-tiles {bx, 31-bx}
// of 64 rows -> uniform 33 kt-iterations. Wave owns 16 q rows. KBLK=64, dbuf LDS, T14.
// Swapped QK^T (lane-local softmax rows), exp2 domain (Q pre-scaled), T13 defer-rescale.
__global__ __launch_bounds__(256) void attn_kernel(const short* __restrict__ Q,
                                                   const short* __restrict__ K,
                                                   const short* __restrict__ Vt,
                                                   short* __restrict__ O) {
  __shared__ short Ks[2][64][72];
  __shared__ short Vs[2][64][72];
  __shared__ short Ps[4][16][72];
  const int t = threadIdx.x;
  const int wid = t >> 6, lane = t & 63;
  const int lrow = lane & 15, lk = lane >> 4;
  // XCD swizzle: all 16 q-blocks of one bh land on one XCD
  const int lin = blockIdx.x + 16 * blockIdx.y;  // 0..511
  const int xcd = lin & 7, idx = lin >> 3;
  const int bh = xcd * 4 + (idx >> 4);
  const int bx = idx & 15;
  const int b = bh >> 4, h = bh & 15;
  const size_t base = (size_t)b * SEQL * DM + (size_t)h * DK;  // Q,K,O
  const size_t vbase = (size_t)bh * DK * SEQL;                 // Vt
  const int c0 = t, c1 = 256 + t;
  const int kr0 = c0 >> 3, ko0 = (c0 & 7) * 8;
  const int kr1 = c1 >> 3, ko1 = (c1 & 7) * 8;
  const float THR = 11.5416f;  // 8 * log2(e)

#pragma unroll
  for (int pi = 0; pi < 2; ++pi) {
    const int qt = pi ? (31 - bx) : bx;
    const int qmin = qt * 64 + wid * 16;

    bf16x8 aq[2];
#pragma unroll
    for (int c = 0; c < 2; ++c)
      aq[c] = *reinterpret_cast<const bf16x8*>(
          &Q[base + (size_t)(qmin + lrow) * DM + c * 32 + lk * 8]);

    f32x4 oacc[4];
#pragma unroll
    for (int g = 0; g < 4; ++g) oacc[g] = (f32x4){0.f, 0.f, 0.f, 0.f};
    float mrow = -1e30f, lsum = 0.f;  // per-lane partial; q-row = qmin+lrow

    __syncthreads();  // guard buffer reuse across passes
    {
      bf16x8 k0 = *reinterpret_cast<const bf16x8*>(&K[base + (size_t)kr0 * DM + ko0]);
      bf16x8 k1 = *reinterpret_cast<const bf16x8*>(&K[base + (size_t)kr1 * DM + ko1]);
      bf16x8 v0 = *reinterpret_cast<const bf16x8*>(&Vt[vbase + (size_t)kr0 * SEQL + ko0]);
      bf16x8 v1 = *reinterpret_cast<const bf16x8*>(&Vt[vbase + (size_t)kr1 * SEQL + ko1]);
      *reinterpret_cast<bf16x8*>(&Ks[0][kr0][ko0]) = k0;
      *reinterpret_cast<bf16x8*>(&Ks[0][kr1][ko1]) = k1;
      *reinterpret_cast<bf16x8*>(&Vs[0][kr0][ko0]) = v0;
      *reinterpret_cast<bf16x8*>(&Vs[0][kr1][ko1]) = v1;
    }
    int cur = 0;
    bf16x8 kreg0, kreg1, vreg0, vreg1;
    for (int kt = 0; kt <= qt; ++kt) {
      __syncthreads();  // buf[cur] ready
      if (kt < qt) {    // issue next tile's loads (T14)
        size_t ko = (size_t)(kt + 1) * 64;
        kreg0 = *reinterpret_cast<const bf16x8*>(&K[base + (ko + kr0) * DM + ko0]);
        kreg1 = *reinterpret_cast<const bf16x8*>(&K[base + (ko + kr1) * DM + ko1]);
        vreg0 = *reinterpret_cast<const bf16x8*>(&Vt[vbase + (size_t)kr0 * SEQL + ko + ko0]);
        vreg1 = *reinterpret_cast<const bf16x8*>(&Vt[vbase + (size_t)kr1 * SEQL + ko + ko1]);
      }
      const bool active = (kt * 64 <= qmin + 15);  // wave-uniform
      if (active) {
        // S^T = K Q^T : lane holds S[q=qmin+lrow][k=kt*64+g*16+lk*4+r] (exp2 domain)
        f32x4 st[4];
        __builtin_amdgcn_s_setprio(1);
#pragma unroll
        for (int g = 0; g < 4; ++g) {
          bf16x8 kf0 = *reinterpret_cast<const bf16x8*>(&Ks[cur][g * 16 + lrow][lk * 8]);
          bf16x8 kf1 = *reinterpret_cast<const bf16x8*>(&Ks[cur][g * 16 + lrow][32 + lk * 8]);
          f32x4 z = (f32x4){0.f, 0.f, 0.f, 0.f};
          z = __builtin_amdgcn_mfma_f32_16x16x32_bf16(kf0, aq[0], z, 0, 0, 0);
          st[g] = __builtin_amdgcn_mfma_f32_16x16x32_bf16(kf1, aq[1], z, 0, 0, 0);
        }
        __builtin_amdgcn_s_setprio(0);
        const int qg = qmin + lrow;
        if (kt == qt) {  // only diagonal tile needs masking
#pragma unroll
          for (int g = 0; g < 4; ++g)
#pragma unroll
            for (int r = 0; r < 4; ++r)
              if (kt * 64 + g * 16 + lk * 4 + r > qg) st[g][r] = -1e30f;
        }
        // local max (compiler fuses to v_max3)
        float pmax = st[0][0];
#pragma unroll
        for (int g = 0; g < 4; ++g)
#pragma unroll
          for (int r = 0; r < 4; ++r) pmax = fmaxf(pmax, st[g][r]);
        // T13: skip rescale when max didn't grow past threshold (common case)
        if (!__all(pmax <= mrow + THR)) {
          float mx = pmax;
          mx = fmaxf(mx, __shfl_xor(mx, 16));
          mx = fmaxf(mx, __shfl_xor(mx, 32));
          float mnew = fmaxf(mrow, mx);
          float alpha = exp2f(mrow - mnew);
          lsum *= alpha;
          float alr[4];
#pragma unroll
          for (int r = 0; r < 4; ++r) alr[r] = __shfl(alpha, lk * 4 + r);
#pragma unroll
          for (int g = 0; g < 4; ++g)
#pragma unroll
            for (int r = 0; r < 4; ++r) oacc[g][r] *= alr[r];
          mrow = mnew;
        }
        float p[4][4], psum = 0.f;
#pragma unroll
        for (int g = 0; g < 4; ++g)
#pragma unroll
          for (int r = 0; r < 4; ++r) {
            float e = exp2f(st[g][r] - mrow);
            p[g][r] = e;
            psum += e;
          }
        lsum += psum;  // per-lane partial; reduced at epilogue
        // P -> per-wave LDS slice -> A-frag
#pragma unroll
        for (int g = 0; g < 4; ++g) {
          uint2 wv = make_uint2(pk2(p[g][0], p[g][1]), pk2(p[g][2], p[g][3]));
          *reinterpret_cast<uint2*>(&Ps[wid][lrow][g * 16 + lk * 4]) = wv;
        }
        asm volatile("s_waitcnt lgkmcnt(0)" ::: "memory");
        __builtin_amdgcn_sched_barrier(0);
        bf16x8 pa0 = *reinterpret_cast<const bf16x8*>(&Ps[wid][lrow][lk * 8]);
        bf16x8 pa1 = *reinterpret_cast<const bf16x8*>(&Ps[wid][lrow][32 + lk * 8]);
        __builtin_amdgcn_s_setprio(1);
#pragma unroll
        for (int g = 0; g < 4; ++g) {
          bf16x8 vf0 = *reinterpret_cast<const bf16x8*>(&Vs[cur][g * 16 + lrow][lk * 8]);
          bf16x8 vf1 = *reinterpret_cast<const bf16x8*>(&Vs[cur][g * 16 + lrow][32 + lk * 8]);
          oacc[g] = __builtin_amdgcn_mfma_f32_16x16x32_bf16(pa0, vf0, oacc[g], 0, 0, 0);
          oacc[g] = __builtin_amdgcn_mfma_f32_16x16x32_bf16(pa1, vf1, oacc[g], 0, 0, 0);
        }
        __builtin_amdgcn_s_setprio(0);
      }
      if (kt < qt) {  // write next tile at iteration tail
        *reinterpret_cast<bf16x8*>(&Ks[cur ^ 1][kr0][ko0]) = kreg0;
        *reinterpret_cast<bf16x8*>(&Ks[cur ^ 1][kr1][ko1]) = kreg1;
        *reinterpret_cast<bf16x8*>(&Vs[cur ^ 1][kr0][ko0]) = vreg0;
        *reinterpret_cast<bf16x8*>(&Vs[cur ^ 1][kr1][ko1]) = vreg1;
      }
      cur ^= 1;
    }
    // epilogue: reduce per-lane partial lsum across the 4 lanes sharing lrow
    lsum += __shfl_xor(lsum, 16);
    lsum += __shfl_xor(lsum, 32);
    float lr[4];
#pragma unroll
    for (int r = 0; r < 4; ++r) lr[r] = 1.0f / __shfl(lsum, lk * 4 + r);
#pragma unroll
    for (int g = 0; g < 4; ++g)
#pragma unroll
      for (int r = 0; r < 4; ++r)
        O[base + (size_t)(qmin + lk * 4 + r) * DM + g * 16 + lrow] = f2bf(oacc[g][r] * lr[r]);
  }
}

// ---------------- host launch ----------------
extern "C" void kernel_launch(void* const* d_in, const int* in_sizes, int n_in,
                              void* d_out, int out_size, void* d_ws, size_t ws_size,
                              hipStream_t stream) {
  const float* x = (const float*)d_in[0];
  const float* wq = (const float*)d_in[1];
  const float* wk = (const float*)d_in[2];
  const float* wv = (const float*)d_in[3];
  const float* wo = (const float*)d_in[4];
  const int* tpos = (const int*)d_in[5];
  float* out = (float*)d_out;

  char* w = (char*)d_ws;
  short* xb = (short*)w;  w += (size_t)NR * DM * 2;
  short* wqb = (short*)w; w += (size_t)DM * DM * 2;
  short* wkb = (short*)w; w += (size_t)DM * DM * 2;
  short* wvb = (short*)w; w += (size_t)DM * DM * 2;
  short* wob = (short*)w; w += (size_t)DM * DM * 2;
  short* Qb = (short*)w;  w += (size_t)NR * DM * 2;
  short* Kb = (short*)w;  w += (size_t)NR * DM * 2;
  short* Vb = (short*)w;  w += (size_t)NR * DM * 2;
  short* Ob = (short*)w;  w += (size_t)NR * DM * 2;
  float2* tab = (float2*)w;
  short* Vtb = xb;  // alias: xb's last use is qkv_gemm; Vt produced after

  cvt_all<<<dim3(DM * DM / 1024, 8), 256, 0, stream>>>(x, wq, wk, wv, wo, xb, wqb, wkb, wvb, wob);
  rope_table_kernel<<<2048 * 32 / 256, 256, 0, stream>>>(tab);
  qkv_gemm_kernel<<<dim3(24, NR / 128), 256, 0, stream>>>(xb, wqb, wkb, wvb, Qb, Kb, Vb);
  rope_apply_kernel<<<dim3(NR * DM / 8 / 256, 2), 256, 0, stream>>>(Qb, Kb, tpos, tab);
  vt_transpose_kernel<<<dim3(SEQL / 64, NB * NH), 256, 0, stream>>>(Vb, Vtb);
  attn_kernel<<<dim3(16, 32), 256, 0, stream>>>(Qb, Kb, Vtb, Ob);
  out_gemm_kernel<<<dim3(DM / 128, NR / 128), 256, 0, stream>>>(Ob, wob, out);
}

// Round 5
// 133.864 us; speedup vs baseline: 2.2408x; 1.0175x over previous
//
#include <hip/hip_runtime.h>
#include <cstdint>
#include <cstddef>

#define NH 16
#define DK 64
#define DM 1024
#define SEQL 2048
#define NB 2
#define NR (NB * SEQL)   // 4096 token rows

typedef short bf16x8 __attribute__((ext_vector_type(8)));
typedef float f32x4 __attribute__((ext_vector_type(4)));

static __device__ __forceinline__ float bf2f(short u) {
  union { unsigned int i; float f; } x;
  x.i = ((unsigned int)(unsigned short)u) << 16;
  return x.f;
}
static __device__ __forceinline__ short f2bf(float f) {
  union { unsigned int i; float f; } x;
  x.f = f;
  unsigned int r = x.i + 0x7fffu + ((x.i >> 16) & 1u);  // RNE
  return (short)(r >> 16);
}
// HW packed f32->bf16 (RNE), T12 recipe: no builtin on gfx950
static __device__ __forceinline__ unsigned cvtpk(float a, float b) {
  unsigned r;
  asm("v_cvt_pk_bf16_f32 %0, %1, %2" : "=v"(r) : "v"(a), "v"(b));
  return r;
}

static __device__ __forceinline__ void store_out(float* p, float v) { *p = v; }
static __device__ __forceinline__ void store_out(short* p, float v) { *p = f2bf(v); }

// async global->LDS, 16B per lane; lds base wave-uniform (HW adds lane*16)
static __device__ __forceinline__ void gload16(const short* g, short* l) {
  __builtin_amdgcn_global_load_lds((const __attribute__((address_space(1))) void*)g,
                                   (__attribute__((address_space(3))) void*)l, 16, 0, 0);
}

// ---------------- all fp32 -> bf16 converts in one launch ----------------
__global__ void cvt_all(const float* __restrict__ x, const float* __restrict__ w0,
                        const float* __restrict__ w1, const float* __restrict__ w2,
                        const float* __restrict__ w3, short* __restrict__ xb,
                        short* __restrict__ o0, short* __restrict__ o1,
                        short* __restrict__ o2, short* __restrict__ o3) {
  int y = blockIdx.y;
  const float* in;
  short* out;
  if (y < 4) { in = x + (size_t)y * DM * DM; out = xb + (size_t)y * DM * DM; }
  else if (y == 4) { in = w0; out = o0; }
  else if (y == 5) { in = w1; out = o1; }
  else if (y == 6) { in = w2; out = o2; }
  else { in = w3; out = o3; }
  int i = (blockIdx.x * blockDim.x + threadIdx.x) * 4;
  float4 v = *reinterpret_cast<const float4*>(in + i);
  short4 o;
  o.x = f2bf(v.x); o.y = f2bf(v.y); o.z = f2bf(v.z); o.w = f2bf(v.w);
  *reinterpret_cast<short4*>(out + i) = o;
}

// ---------------- RoPE cos/sin table: [2048 pos][32 freq] ----------------
__global__ void rope_table_kernel(float2* __restrict__ tab) {
  int idx = blockIdx.x * blockDim.x + threadIdx.x;  // pos*32 + j
  int pos = idx >> 5, j = idx & 31;
  float freq = powf(10000.0f, -(float)j / 32.0f);   // theta^(-2j/64)
  float ang = (float)pos * freq;
  tab[idx] = make_float2(cosf(ang), sinf(ang));
}

// ---------------- RoPE apply, vectorized bf16x8 (4 pairs/thread) ----------------
// Q additionally pre-scaled by 0.125*log2(e) (softmax works in exp2 domain).
__global__ void rope_apply_kernel(short* __restrict__ Qb, short* __restrict__ Kb,
                                  const int* __restrict__ pos, const float2* __restrict__ tab) {
  short* buf = blockIdx.y ? Kb : Qb;
  const float scale = blockIdx.y ? 1.0f : 0.1803368801f;  // 0.125*log2e
  int gid = blockIdx.x * blockDim.x + threadIdx.x;        // [0, NR*DM/8)
  int elem = gid * 8;
  int row = elem >> 10, off = elem & 1023;
  int j0 = (off & 63) >> 1;
  short* ptr = buf + (size_t)row * DM + off;
  bf16x8 v = *reinterpret_cast<bf16x8*>(ptr);
  const float2* tp = &tab[pos[row] * 32 + j0];
  bf16x8 o;
#pragma unroll
  for (int q = 0; q < 4; ++q) {
    float2 cs = tp[q];
    float xe = bf2f(v[2 * q]), xo = bf2f(v[2 * q + 1]);
    o[2 * q] = f2bf((xe * cs.x - xo * cs.y) * scale);
    o[2 * q + 1] = f2bf((xe * cs.y + xo * cs.x) * scale);
  }
  *reinterpret_cast<bf16x8*>(ptr) = o;
}

// ---------------- V transpose: V[b*S+s][h*64+d] -> Vt[(bh*64+d)][s] ----------------
__global__ __launch_bounds__(256) void vt_transpose_kernel(const short* __restrict__ V,
                                                           short* __restrict__ Vt) {
  __shared__ short tile[64][64];
  const int t = threadIdx.x;
  const int bh = blockIdx.y, b = bh >> 4, h = bh & 15;
  const int st = blockIdx.x * 64;
#pragma unroll
  for (int p = 0; p < 2; ++p) {
    int c = p * 256 + t;
    int srow = c >> 3, ch = c & 7;
    int chs = ch ^ ((srow >> 3) & 7);  // swizzle chunk index
    *reinterpret_cast<bf16x8*>(&tile[srow][chs * 8]) =
        *reinterpret_cast<const bf16x8*>(&V[(size_t)(b * SEQL + st + srow) * DM + h * 64 + ch * 8]);
  }
  __syncthreads();
#pragma unroll
  for (int p = 0; p < 2; ++p) {
    int c = p * 256 + t;
    int drow = c >> 3, soff = (c & 7) * 8;
    short o[8];
#pragma unroll
    for (int e = 0; e < 8; ++e) {
      int srow = soff + e;
      int col = (((drow >> 3) ^ ((srow >> 3) & 7)) << 3) + (drow & 7);
      o[e] = tile[srow][col];
    }
    *reinterpret_cast<bf16x8*>(&Vt[(size_t)(bh * DK + drow) * SEQL + st + soff]) =
        *reinterpret_cast<bf16x8*>(o);
  }
}

// ---------------- bf16 GEMM (m97 structure): C[M][N] = A[M][K] * B[N][K]^T ----------------
template <typename OutT>
static __device__ __forceinline__ void gemm_body(const short* __restrict__ A,
                                                 const short* __restrict__ B,
                                                 OutT* __restrict__ C,
                                                 int m0, int n0, int N, int K) {
  __shared__ short As[128][32];
  __shared__ short Bs[128][32];
  const int t = threadIdx.x;
  const int wid = t >> 6, lane = t & 63;
  const int wr = wid >> 1, wc = wid & 1;
  const int lrow = lane & 15, lk = lane >> 4;

  f32x4 acc[4][4];
#pragma unroll
  for (int i = 0; i < 4; ++i)
#pragma unroll
    for (int j = 0; j < 4; ++j) acc[i][j] = (f32x4){0.f, 0.f, 0.f, 0.f};

  for (int k0 = 0; k0 < K; k0 += 32) {
    __syncthreads();
#pragma unroll
    for (int p = 0; p < 2; ++p) {
      int c = p * 256 + t;
      int row = c >> 2, kc = (c & 3) * 8;
      gload16(&A[(size_t)(m0 + row) * K + k0 + kc], &As[0][0] + (size_t)(p * 256 + wid * 64) * 8);
      gload16(&B[(size_t)(n0 + row) * K + k0 + kc], &Bs[0][0] + (size_t)(p * 256 + wid * 64) * 8);
    }
    __syncthreads();
    bf16x8 af[4], bfr[4];
#pragma unroll
    for (int i = 0; i < 4; ++i) {
      af[i] = *reinterpret_cast<const bf16x8*>(&As[wr * 64 + i * 16 + lrow][lk * 8]);
      bfr[i] = *reinterpret_cast<const bf16x8*>(&Bs[wc * 64 + i * 16 + lrow][lk * 8]);
    }
    __builtin_amdgcn_s_setprio(1);
#pragma unroll
    for (int i = 0; i < 4; ++i)
#pragma unroll
      for (int j = 0; j < 4; ++j)
        acc[i][j] = __builtin_amdgcn_mfma_f32_16x16x32_bf16(af[i], bfr[j], acc[i][j], 0, 0, 0);
    __builtin_amdgcn_s_setprio(0);
  }
#pragma unroll
  for (int i = 0; i < 4; ++i)
#pragma unroll
    for (int j = 0; j < 4; ++j) {
      int row = m0 + wr * 64 + i * 16 + lk * 4;
      int col = n0 + wc * 64 + j * 16 + lrow;
#pragma unroll
      for (int r = 0; r < 4; ++r) store_out(&C[(size_t)(row + r) * N + col], acc[i][j][r]);
    }
}

__global__ __launch_bounds__(256) void qkv_gemm_kernel(
    const short* __restrict__ X, const short* __restrict__ Wq, const short* __restrict__ Wk,
    const short* __restrict__ Wv, short* __restrict__ Q, short* __restrict__ K,
    short* __restrict__ V) {
  int nb = blockIdx.x;
  const short* B = (nb < 8) ? Wq : (nb < 16) ? Wk : Wv;
  short* C = (nb < 8) ? Q : (nb < 16) ? K : V;
  gemm_body<short>(X, B, C, blockIdx.y * 128, (nb & 7) * 128, DM, DM);
}

__global__ __launch_bounds__(256) void out_gemm_kernel(const short* __restrict__ A,
                                                       const short* __restrict__ W,
                                                       float* __restrict__ C) {
  gemm_body<float>(A, W, C, blockIdx.y * 128, blockIdx.x * 128, DM, DM);
}

// ---------------- causal flash attention ----------------
// grid 1024 x 256thr (4 waves). One 64-row q-tile per block (UNPAIRED -> 4 blocks/CU
// co-resident = 16 waves/CU). Single-buffer LDS (27.6KB) + T14 reg prefetch, 2 barriers/iter.
// qt-descending dispatch (longest first) + XCD swizzle (4 bh per XCD -> K/V/Q fit L2).
// Swapped QK^T (lane-local softmax), exp2 domain (Q pre-scaled), T13 defer-rescale.
__global__ __launch_bounds__(256) void attn_kernel(const short* __restrict__ Q,
                                                   const short* __restrict__ K,
                                                   const short* __restrict__ Vt,
                                                   short* __restrict__ O) {
  __shared__ short Ks[64][72];
  __shared__ short Vs[64][72];
  __shared__ short Ps[4][16][72];
  const int t = threadIdx.x;
  const int wid = t >> 6, lane = t & 63;
  const int lrow = lane & 15, lk = lane >> 4;
  const int lin = blockIdx.x;            // 0..1023
  const int xcd = lin & 7, idx = lin >> 3;
  const int qt = 31 - (idx >> 2);        // long blocks dispatch first
  const int bh = xcd * 4 + (idx & 3);    // 4 bh per XCD (L2 locality)
  const int b = bh >> 4, h = bh & 15;
  const size_t base = (size_t)b * SEQL * DM + (size_t)h * DK;  // Q,K,O
  const size_t vbase = (size_t)bh * DK * SEQL;                 // Vt
  const int kr0 = t >> 3, kr1 = 32 + (t >> 3), ko0 = (t & 7) * 8;
  const float THR = 11.5416f;  // 8 * log2(e)
  const int qmin = qt * 64 + wid * 16;

  bf16x8 aq[2];
#pragma unroll
  for (int c = 0; c < 2; ++c)
    aq[c] = *reinterpret_cast<const bf16x8*>(
        &Q[base + (size_t)(qmin + lrow) * DM + c * 32 + lk * 8]);

  f32x4 oacc[4];
#pragma unroll
  for (int g = 0; g < 4; ++g) oacc[g] = (f32x4){0.f, 0.f, 0.f, 0.f};
  float mrow = -1e30f, lsum = 0.f;  // per-lane partial; q-row = qmin+lrow

  // prologue: stage tile 0
  {
    bf16x8 k0 = *reinterpret_cast<const bf16x8*>(&K[base + (size_t)kr0 * DM + ko0]);
    bf16x8 k1 = *reinterpret_cast<const bf16x8*>(&K[base + (size_t)kr1 * DM + ko0]);
    bf16x8 v0 = *reinterpret_cast<const bf16x8*>(&Vt[vbase + (size_t)kr0 * SEQL + ko0]);
    bf16x8 v1 = *reinterpret_cast<const bf16x8*>(&Vt[vbase + (size_t)kr1 * SEQL + ko0]);
    *reinterpret_cast<bf16x8*>(&Ks[kr0][ko0]) = k0;
    *reinterpret_cast<bf16x8*>(&Ks[kr1][ko0]) = k1;
    *reinterpret_cast<bf16x8*>(&Vs[kr0][ko0]) = v0;
    *reinterpret_cast<bf16x8*>(&Vs[kr1][ko0]) = v1;
  }
  bf16x8 kreg0, kreg1, vreg0, vreg1;
  for (int kt = 0; kt <= qt; ++kt) {
    __syncthreads();  // staged tile kt visible to all waves
    if (kt < qt) {    // T14: issue next tile's loads; HBM/L2 latency hides under compute
      size_t ko = (size_t)(kt + 1) * 64;
      kreg0 = *reinterpret_cast<const bf16x8*>(&K[base + (ko + kr0) * DM + ko0]);
      kreg1 = *reinterpret_cast<const bf16x8*>(&K[base + (ko + kr1) * DM + ko0]);
      vreg0 = *reinterpret_cast<const bf16x8*>(&Vt[vbase + (size_t)kr0 * SEQL + ko + ko0]);
      vreg1 = *reinterpret_cast<const bf16x8*>(&Vt[vbase + (size_t)kr1 * SEQL + ko + ko0]);
    }
    // S^T = K Q^T : lane holds S[q=qmin+lrow][k=kt*64+g*16+lk*4+r] (exp2 domain)
    f32x4 st[4];
    __builtin_amdgcn_s_setprio(1);
#pragma unroll
    for (int g = 0; g < 4; ++g) {
      bf16x8 kf0 = *reinterpret_cast<const bf16x8*>(&Ks[g * 16 + lrow][lk * 8]);
      bf16x8 kf1 = *reinterpret_cast<const bf16x8*>(&Ks[g * 16 + lrow][32 + lk * 8]);
      f32x4 z = (f32x4){0.f, 0.f, 0.f, 0.f};
      z = __builtin_amdgcn_mfma_f32_16x16x32_bf16(kf0, aq[0], z, 0, 0, 0);
      st[g] = __builtin_amdgcn_mfma_f32_16x16x32_bf16(kf1, aq[1], z, 0, 0, 0);
    }
    __builtin_amdgcn_s_setprio(0);
    const int qg = qmin + lrow;
    if (kt == qt) {  // only the diagonal tile needs masking
#pragma unroll
      for (int g = 0; g < 4; ++g)
#pragma unroll
        for (int r = 0; r < 4; ++r)
          if (kt * 64 + g * 16 + lk * 4 + r > qg) st[g][r] = -1e30f;
    }
    float pmax = st[0][0];
#pragma unroll
    for (int g = 0; g < 4; ++g)
#pragma unroll
      for (int r = 0; r < 4; ++r) pmax = fmaxf(pmax, st[g][r]);
    // T13: skip rescale when max didn't grow past threshold (common case)
    if (!__all(pmax <= mrow + THR)) {
      float mx = pmax;
      mx = fmaxf(mx, __shfl_xor(mx, 16));
      mx = fmaxf(mx, __shfl_xor(mx, 32));
      float mnew = fmaxf(mrow, mx);
      float alpha = exp2f(mrow - mnew);
      lsum *= alpha;
      float alr[4];
#pragma unroll
      for (int r = 0; r < 4; ++r) alr[r] = __shfl(alpha, lk * 4 + r);
#pragma unroll
      for (int g = 0; g < 4; ++g)
#pragma unroll
        for (int r = 0; r < 4; ++r) oacc[g][r] *= alr[r];
      mrow = mnew;
    }
    float p[4][4], psum = 0.f;
#pragma unroll
    for (int g = 0; g < 4; ++g)
#pragma unroll
      for (int r = 0; r < 4; ++r) {
        float e = exp2f(st[g][r] - mrow);
        p[g][r] = e;
        psum += e;
      }
    lsum += psum;  // per-lane partial; reduced at epilogue
    // P -> per-wave LDS slice -> A-frag (hw packed cvt)
#pragma unroll
    for (int g = 0; g < 4; ++g) {
      uint2 wv = make_uint2(cvtpk(p[g][0], p[g][1]), cvtpk(p[g][2], p[g][3]));
      *reinterpret_cast<uint2*>(&Ps[wid][lrow][g * 16 + lk * 4]) = wv;
    }
    asm volatile("s_waitcnt lgkmcnt(0)" ::: "memory");
    __builtin_amdgcn_sched_barrier(0);
    bf16x8 pa0 = *reinterpret_cast<const bf16x8*>(&Ps[wid][lrow][lk * 8]);
    bf16x8 pa1 = *reinterpret_cast<const bf16x8*>(&Ps[wid][lrow][32 + lk * 8]);
    __builtin_amdgcn_s_setprio(1);
#pragma unroll
    for (int g = 0; g < 4; ++g) {
      bf16x8 vf0 = *reinterpret_cast<const bf16x8*>(&Vs[g * 16 + lrow][lk * 8]);
      bf16x8 vf1 = *reinterpret_cast<const bf16x8*>(&Vs[g * 16 + lrow][32 + lk * 8]);
      oacc[g] = __builtin_amdgcn_mfma_f32_16x16x32_bf16(pa0, vf0, oacc[g], 0, 0, 0);
      oacc[g] = __builtin_amdgcn_mfma_f32_16x16x32_bf16(pa1, vf1, oacc[g], 0, 0, 0);
    }
    __builtin_amdgcn_s_setprio(0);
    __syncthreads();  // all waves done reading tile kt
    if (kt < qt) {    // write next tile (loads have had the whole compute to land)
      *reinterpret_cast<bf16x8*>(&Ks[kr0][ko0]) = kreg0;
      *reinterpret_cast<bf16x8*>(&Ks[kr1][ko0]) = kreg1;
      *reinterpret_cast<bf16x8*>(&Vs[kr0][ko0]) = vreg0;
      *reinterpret_cast<bf16x8*>(&Vs[kr1][ko0]) = vreg1;
    }
  }
  // epilogue: reduce per-lane partial lsum across the 4 lanes sharing lrow
  lsum += __shfl_xor(lsum, 16);
  lsum += __shfl_xor(lsum, 32);
  float lr[4];
#pragma unroll
  for (int r = 0; r < 4; ++r) lr[r] = 1.0f / __shfl(lsum, lk * 4 + r);
#pragma unroll
  for (int g = 0; g < 4; ++g)
#pragma unroll
    for (int r = 0; r < 4; ++r)
      O[base + (size_t)(qmin + lk * 4 + r) * DM + g * 16 + lrow] = f2bf(oacc[g][r] * lr[r]);
}

// ---------------- host launch ----------------
extern "C" void kernel_launch(void* const* d_in, const int* in_sizes, int n_in,
                              void* d_out, int out_size, void* d_ws, size_t ws_size,
                              hipStream_t stream) {
  const float* x = (const float*)d_in[0];
  const float* wq = (const float*)d_in[1];
  const float* wk = (const float*)d_in[2];
  const float* wv = (const float*)d_in[3];
  const float* wo = (const float*)d_in[4];
  const int* tpos = (const int*)d_in[5];
  float* out = (float*)d_out;

  char* w = (char*)d_ws;
  short* xb = (short*)w;  w += (size_t)NR * DM * 2;
  short* wqb = (short*)w; w += (size_t)DM * DM * 2;
  short* wkb = (short*)w; w += (size_t)DM * DM * 2;
  short* wvb = (short*)w; w += (size_t)DM * DM * 2;
  short* wob = (short*)w; w += (size_t)DM * DM * 2;
  short* Qb = (short*)w;  w += (size_t)NR * DM * 2;
  short* Kb = (short*)w;  w += (size_t)NR * DM * 2;
  short* Vb = (short*)w;  w += (size_t)NR * DM * 2;
  short* Ob = (short*)w;  w += (size_t)NR * DM * 2;
  float2* tab = (float2*)w;
  short* Vtb = xb;  // alias: xb's last use is qkv_gemm; Vt produced after

  cvt_all<<<dim3(DM * DM / 1024, 8), 256, 0, stream>>>(x, wq, wk, wv, wo, xb, wqb, wkb, wvb, wob);
  rope_table_kernel<<<2048 * 32 / 256, 256, 0, stream>>>(tab);
  qkv_gemm_kernel<<<dim3(24, NR / 128), 256, 0, stream>>>(xb, wqb, wkb, wvb, Qb, Kb, Vb);
  rope_apply_kernel<<<dim3(NR * DM / 8 / 256, 2), 256, 0, stream>>>(Qb, Kb, tpos, tab);
  vt_transpose_kernel<<<dim3(SEQL / 64, NB * NH), 256, 0, stream>>>(Vb, Vtb);
  attn_kernel<<<1024, 256, 0, stream>>>(Qb, Kb, Vtb, Ob);
  out_gemm_kernel<<<dim3(DM / 128, NR / 128), 256, 0, stream>>>(Ob, wob, out);
}